// Round 4
// baseline (257.081 us; speedup 1.0000x reference)
//
#include <hip/hip_runtime.h>
#include <hip/hip_bf16.h>
#include <stdint.h>

// Problem constants: N=8, T=200, U=50, E=D=J=512, V=500. M = N*T*U = 80000.
#define JD 512
#define VV 500

typedef short short8 __attribute__((ext_vector_type(8)));
typedef short short4v __attribute__((ext_vector_type(4)));
typedef float floatx4 __attribute__((ext_vector_type(4)));

__device__ inline short f2bf(float f) {
    uint32_t u = __float_as_uint(f);
    uint32_t r = (u + 0x7FFFu + ((u >> 16) & 1u)) >> 16;
    return (short)r;
}

__device__ inline float fast_tanh(float x) {
    // tanh(x) = 1 - 2/(exp(2x)+1); v_exp_f32 is exp2 natively.
    float e = __builtin_amdgcn_exp2f(x * 2.8853900817779268f); // 2*log2(e)
    return 1.0f - 2.0f * __builtin_amdgcn_rcpf(e + 1.0f);
}

// ---------------------------------------------------------------------------
// Kernel 1: W_out -> WbF, fragment-native AND wave-contiguous:
//   short index = ((ks*4 + wn)*8 + in)*512 + q4*128 + l16*8 + e
//   holds Wout[v = wn*128 + in*16 + l16][k = ks*32 + q4*8 + e].
// Per (wave wn, k-step ks) the 8 B-fragments are ONE contiguous 8 KB block:
// the k-loop walks WbF with 2 address registers + immediate offsets
// (round-4 change to cut live VGPRs so 4 waves/SIMD fit; round-3's 8
// scattered fragment addresses cost ~16 regs).
// ---------------------------------------------------------------------------
__global__ __launch_bounds__(256) void prep_kernel(
    const float* __restrict__ Wout, short* __restrict__ WbF)
{
    int j = blockIdx.x * 256 + threadIdx.x;   // 0..32767, 8 shorts each
    int l16 = j & 15;
    int q4  = (j >> 4) & 3;
    int in  = (j >> 6) & 7;
    int wn  = (j >> 9) & 3;
    int ks  = j >> 11;                         // 0..15
    int v  = wn * 128 + in * 16 + l16;
    int k0 = ks * 32 + q4 * 8;
    short8 o;
    if (v < VV) {
        const float4* p = (const float4*)(Wout + (size_t)v * JD + k0);
        float4 a = p[0], b = p[1];
        o[0] = f2bf(a.x); o[1] = f2bf(a.y); o[2] = f2bf(a.z); o[3] = f2bf(a.w);
        o[4] = f2bf(b.x); o[5] = f2bf(b.y); o[6] = f2bf(b.z); o[7] = f2bf(b.w);
    } else {
        o = (short8){0,0,0,0,0,0,0,0};
    }
    *(short8*)(WbF + (size_t)j * 8) = o;       // coalesced 16 B/lane
}

// ---------------------------------------------------------------------------
// Kernel 2: projection GEMMs (enc: 1600x512x512, dec: 400x512x512).
// fp32 read + inline bf16 convert while staging to LDS. BM=64 x BN=64 tiles
// -> 256 blocks (1/CU). LDS stride 72 shorts. (unchanged from round 3)
// ---------------------------------------------------------------------------
#define PST 72
__global__ __launch_bounds__(256) void proj_gemm(
    const float* __restrict__ enc, const float* __restrict__ dec,
    const float* __restrict__ Wenc, const float* __restrict__ Wdec,
    const float* __restrict__ b_enc, const float* __restrict__ b_dec,
    float* __restrict__ enc_p, float* __restrict__ dec_p)
{
    __shared__ short As[64 * PST];    // 9,216 B
    __shared__ short Bs[64 * PST];    // 9,216 B
    int bx = blockIdx.x, by = blockIdx.y;
    const float* A; const float* W; const float* bias; float* C; int M;
    if (bx < 25) { A = enc; W = Wenc; bias = b_enc; C = enc_p; M = 1600; }
    else { bx -= 25; A = dec; W = Wdec; bias = b_dec; C = dec_p; M = 400; }

    int tid = threadIdx.x;
    int lane = tid & 63, wv = tid >> 6;
    int wm = wv >> 1, wn = wv & 1;          // 2x2 wave grid, wave tile 32x32
    int l16 = lane & 15, q4 = lane >> 4;

    int ra = tid >> 2, ha = tid & 3;        // stage: row 0..63, 16-float k-chunk
    int m_st = bx * 64 + ra;
    bool valid = m_st < M;
    int wrow = by * 64 + ra;                // always < 512

    floatx4 acc[2][2];
    #pragma unroll
    for (int a = 0; a < 2; a++)
        #pragma unroll
        for (int b = 0; b < 2; b++) acc[a][b] = (floatx4){0.f, 0.f, 0.f, 0.f};

    for (int kk = 0; kk < 8; kk++) {
        int k0 = kk * 64;
        __syncthreads();
        {
            // ---- A tile: 64 rows x 64 k, fp32 -> bf16
            float4 v0 = make_float4(0.f, 0.f, 0.f, 0.f);
            float4 v1 = v0, v2 = v0, v3 = v0;
            if (valid) {
                const float4* p = (const float4*)(A + (size_t)m_st * JD + k0 + ha * 16);
                v0 = p[0]; v1 = p[1]; v2 = p[2]; v3 = p[3];
            }
            short8 o0, o1;
            o0[0] = f2bf(v0.x); o0[1] = f2bf(v0.y); o0[2] = f2bf(v0.z); o0[3] = f2bf(v0.w);
            o0[4] = f2bf(v1.x); o0[5] = f2bf(v1.y); o0[6] = f2bf(v1.z); o0[7] = f2bf(v1.w);
            o1[0] = f2bf(v2.x); o1[1] = f2bf(v2.y); o1[2] = f2bf(v2.z); o1[3] = f2bf(v2.w);
            o1[4] = f2bf(v3.x); o1[5] = f2bf(v3.y); o1[6] = f2bf(v3.z); o1[7] = f2bf(v3.w);
            *(short8*)&As[ra * PST + ha * 16]     = o0;
            *(short8*)&As[ra * PST + ha * 16 + 8] = o1;

            // ---- B tile: 64 rows x 64 k, fp32 -> bf16
            const float4* pb = (const float4*)(W + (size_t)wrow * JD + k0 + ha * 16);
            float4 w0 = pb[0], w1 = pb[1], w2 = pb[2], w3 = pb[3];
            short8 p0, p1;
            p0[0] = f2bf(w0.x); p0[1] = f2bf(w0.y); p0[2] = f2bf(w0.z); p0[3] = f2bf(w0.w);
            p0[4] = f2bf(w1.x); p0[5] = f2bf(w1.y); p0[6] = f2bf(w1.z); p0[7] = f2bf(w1.w);
            p1[0] = f2bf(w2.x); p1[1] = f2bf(w2.y); p1[2] = f2bf(w2.z); p1[3] = f2bf(w2.w);
            p1[4] = f2bf(w3.x); p1[5] = f2bf(w3.y); p1[6] = f2bf(w3.z); p1[7] = f2bf(w3.w);
            *(short8*)&Bs[ra * PST + ha * 16]     = p0;
            *(short8*)&Bs[ra * PST + ha * 16 + 8] = p1;
        }
        __syncthreads();
        #pragma unroll
        for (int h2 = 0; h2 < 2; h2++) {
            short8 af[2], bf[2];
            #pragma unroll
            for (int im = 0; im < 2; im++)
                af[im] = *(const short8*)&As[(wm * 32 + im * 16 + l16) * PST + h2 * 32 + q4 * 8];
            #pragma unroll
            for (int in = 0; in < 2; in++)
                bf[in] = *(const short8*)&Bs[(wn * 32 + in * 16 + l16) * PST + h2 * 32 + q4 * 8];
            #pragma unroll
            for (int im = 0; im < 2; im++)
                #pragma unroll
                for (int in = 0; in < 2; in++)
                    acc[im][in] = __builtin_amdgcn_mfma_f32_16x16x32_bf16(
                        af[im], bf[in], acc[im][in], 0, 0, 0);
        }
    }
    #pragma unroll
    for (int im = 0; im < 2; im++) {
        int mb = bx * 64 + wm * 32 + im * 16 + q4 * 4;
        #pragma unroll
        for (int rr = 0; rr < 4; rr++) {
            int m = mb + rr;
            if (m < M) {
                #pragma unroll
                for (int in = 0; in < 2; in++) {
                    int j = by * 64 + wn * 32 + in * 16 + l16;
                    C[(size_t)m * JD + j] = acc[im][in][rr] + bias[j];
                }
            }
        }
    }
}

// ---------------------------------------------------------------------------
// Kernel 3: FUSED act + vocab GEMM.
// v4: occupancy fix. Round-3 waves held acc[4][8] = 128 AGPRs + ~124 VGPRs
// (unified file on gfx950) -> only 2 waves/SIMD; all pipes idled at ~20%
// waiting on L2. Now: 512 threads / 8 waves (2x4), wave tile 32x128 ->
// acc[2][8] = 64 AGPR; B single-buffered (TLP from 4 waves/SIMD replaces the
// register double-buffer, -32 VGPR); wave-contiguous WbF (2 addr pairs +
// immediate offsets). Target <=128 regs/wave -> 2 blocks x 8 waves = 16
// waves/CU. Per ks-step: 16 MFMAs (~78 cyc) x 4 waves/SIMD = 312 cyc of
// MFMA cover vs ~200 cyc L2 latency -> pipe can saturate. out stores are
// nontemporal (160 MB write-once; keep L2 for WbF/enc_p).
// ---------------------------------------------------------------------------
#define AST 520
__global__ __launch_bounds__(512, 4) void fused_joiner(
    const float* __restrict__ enc_p, const float* __restrict__ dec_p,
    const short* __restrict__ WbF, const float* __restrict__ b_out,
    float* __restrict__ out)
{
    __shared__ short As[64 * AST];   // 66,560 B -> LDS allows 2 blocks/CU
    int tid = threadIdx.x;
    int bx = blockIdx.x;

    // ---- Phase 1: act tile (64 m-rows x 512 j) -> LDS
    {
        int rsub = tid >> 7;            // 0..3 rows per pass
        int jf = (tid & 127) * 4;       // fp32 j offset, coalesced per row
        #pragma unroll 4
        for (int pass = 0; pass < 16; pass++) {
            int row = pass * 4 + rsub;
            int m = bx * 64 + row;
            int er = m / 50;            // n*200 + t
            int n  = m / 10000;
            int dr = n * 50 + (m - er * 50);
            float4 e = *(const float4*)(enc_p + (size_t)er * JD + jf);
            float4 d = *(const float4*)(dec_p + (size_t)dr * JD + jf);
            short4v o;
            o[0] = f2bf(fast_tanh(e.x + d.x));
            o[1] = f2bf(fast_tanh(e.y + d.y));
            o[2] = f2bf(fast_tanh(e.z + d.z));
            o[3] = f2bf(fast_tanh(e.w + d.w));
            *(short4v*)&As[row * AST + jf] = o;
        }
    }
    __syncthreads();

    // ---- Phase 2: GEMM out[64 x 512] = act x Wb^T over K=512
    int lane = tid & 63, wv = tid >> 6;   // 8 waves
    int wm = wv >> 2, wn = wv & 3;        // 2 x 4 wave grid, wave tile 32x128
    int l16 = lane & 15, q4 = lane >> 4;

    floatx4 acc[2][8];
    #pragma unroll
    for (int a = 0; a < 2; a++)
        #pragma unroll
        for (int b = 0; b < 8; b++) acc[a][b] = (floatx4){0.f, 0.f, 0.f, 0.f};

    int abase[2];
    #pragma unroll
    for (int im = 0; im < 2; im++)
        abase[im] = (wm * 32 + im * 16 + l16) * AST + q4 * 8;

    // Wave-contiguous WbF: per (wn, ks) the 8 fragments live in one 8 KB
    // block at (ks*4 + wn)*4096 shorts; lane offset q4*128 + l16*8.
    const short* wp = WbF + wn * 4096 + q4 * 128 + l16 * 8;

    for (int ks = 0; ks < 16; ks++) {
        short8 bfr[8];
        #pragma unroll
        for (int in = 0; in < 8; in++)
            bfr[in] = *(const short8*)(wp + in * 512);   // imm offsets
        short8 af[2];
        int k0 = ks * 32;
        #pragma unroll
        for (int im = 0; im < 2; im++)
            af[im] = *(const short8*)&As[abase[im] + k0];
        #pragma unroll
        for (int im = 0; im < 2; im++)
            #pragma unroll
            for (int in = 0; in < 8; in++)
                acc[im][in] = __builtin_amdgcn_mfma_f32_16x16x32_bf16(
                    af[im], bfr[in], acc[im][in], 0, 0, 0);
        wp += 16384;                                     // 4 * 4096 shorts
    }

    // ---- Epilogue: bias + nontemporal store (guard v < 500)
    float bo[8];
    #pragma unroll
    for (int in = 0; in < 8; in++) {
        int v = wn * 128 + in * 16 + l16;
        bo[in] = (v < VV) ? b_out[v] : 0.f;
    }
    #pragma unroll
    for (int im = 0; im < 2; im++) {
        int mb = bx * 64 + wm * 32 + im * 16 + q4 * 4;
        #pragma unroll
        for (int rr = 0; rr < 4; rr++) {
            size_t orow = (size_t)(mb + rr) * VV;
            #pragma unroll
            for (int in = 0; in < 8; in++) {
                int v = wn * 128 + in * 16 + l16;
                if (v < VV)
                    __builtin_nontemporal_store(acc[im][in][rr] + bo[in],
                                                &out[orow + v]);
            }
        }
    }
}

// ---------------------------------------------------------------------------
extern "C" void kernel_launch(void* const* d_in, const int* in_sizes, int n_in,
                              void* d_out, int out_size, void* d_ws, size_t ws_size,
                              hipStream_t stream)
{
    const float* enc   = (const float*)d_in[0];
    const float* dec   = (const float*)d_in[1];
    const float* Wenc  = (const float*)d_in[2];
    const float* b_enc = (const float*)d_in[3];
    const float* Wdec  = (const float*)d_in[4];
    const float* b_dec = (const float*)d_in[5];
    const float* Wout  = (const float*)d_in[6];
    const float* b_out = (const float*)d_in[7];
    float* out = (float*)d_out;

    // ws layout (bytes): ~4.6 MB total
    char* ws = (char*)d_ws;
    short* WbF   = (short*)(ws + 0);          // 512*512 bf16 = 524,288 B
    float* enc_p = (float*)(ws + 524288);     // 1600*512 f32 = 3,276,800 B
    float* dec_p = (float*)(ws + 3801088);    //  400*512 f32 =   819,200 B

    prep_kernel<<<128, 256, 0, stream>>>(Wout, WbF);
    proj_gemm<<<dim3(32, 8), 256, 0, stream>>>(enc, dec, Wenc, Wdec,
                                               b_enc, b_dec, enc_p, dec_p);
    fused_joiner<<<1250, 512, 0, stream>>>(enc_p, dec_p, WbF, b_out, out);
}

// Round 6
// 238.336 us; speedup vs baseline: 1.0786x; 1.0786x over previous
//
#include <hip/hip_runtime.h>
#include <hip/hip_bf16.h>
#include <stdint.h>

// Problem constants: N=8, T=200, U=50, E=D=J=512, V=500. M = N*T*U = 80000.
#define JD 512
#define VV 500

typedef short short8 __attribute__((ext_vector_type(8)));
typedef short short4v __attribute__((ext_vector_type(4)));
typedef float floatx4 __attribute__((ext_vector_type(4)));

__device__ inline short f2bf(float f) {
    uint32_t u = __float_as_uint(f);
    uint32_t r = (u + 0x7FFFu + ((u >> 16) & 1u)) >> 16;
    return (short)r;
}

__device__ inline float fast_tanh(float x) {
    // tanh(x) = 1 - 2/(exp(2x)+1); v_exp_f32 is exp2 natively.
    float e = __builtin_amdgcn_exp2f(x * 2.8853900817779268f); // 2*log2(e)
    return 1.0f - 2.0f * __builtin_amdgcn_rcpf(e + 1.0f);
}

// ---------------------------------------------------------------------------
// Kernel 1: W_out -> WbF, fragment-native order (unchanged from round 3/4):
//   short index = ((ks*4 + wn)*8 + in)*512 + q4*128 + l16*8 + e
//   holds Wout[v = wn*128 + in*16 + l16][k = ks*32 + q4*8 + e], zero-padded
//   v 500..511. A wave's B-fragment load is one contiguous 1 KiB read.
// ---------------------------------------------------------------------------
__global__ __launch_bounds__(256) void prep_kernel(
    const float* __restrict__ Wout, short* __restrict__ WbF)
{
    int j = blockIdx.x * 256 + threadIdx.x;   // 0..32767, 8 shorts each
    int l16 = j & 15;
    int q4  = (j >> 4) & 3;
    int in  = (j >> 6) & 7;
    int wn  = (j >> 9) & 3;
    int ks  = j >> 11;                         // 0..15
    int v  = wn * 128 + in * 16 + l16;
    int k0 = ks * 32 + q4 * 8;
    short8 o;
    if (v < VV) {
        const float4* p = (const float4*)(Wout + (size_t)v * JD + k0);
        float4 a = p[0], b = p[1];
        o[0] = f2bf(a.x); o[1] = f2bf(a.y); o[2] = f2bf(a.z); o[3] = f2bf(a.w);
        o[4] = f2bf(b.x); o[5] = f2bf(b.y); o[6] = f2bf(b.z); o[7] = f2bf(b.w);
    } else {
        o = (short8){0,0,0,0,0,0,0,0};
    }
    *(short8*)(WbF + (size_t)j * 8) = o;       // coalesced 16 B/lane
}

// ---------------------------------------------------------------------------
// Kernel 2: projection GEMMs (enc: 1600x512x512, dec: 400x512x512).
// fp32 read + inline bf16 convert while staging to LDS. BM=64 x BN=64 tiles
// -> 256 blocks (1/CU). LDS stride 72 shorts. (unchanged from round 3/4)
// ---------------------------------------------------------------------------
#define PST 72
__global__ __launch_bounds__(256) void proj_gemm(
    const float* __restrict__ enc, const float* __restrict__ dec,
    const float* __restrict__ Wenc, const float* __restrict__ Wdec,
    const float* __restrict__ b_enc, const float* __restrict__ b_dec,
    float* __restrict__ enc_p, float* __restrict__ dec_p)
{
    __shared__ short As[64 * PST];    // 9,216 B
    __shared__ short Bs[64 * PST];    // 9,216 B
    int bx = blockIdx.x, by = blockIdx.y;
    const float* A; const float* W; const float* bias; float* C; int M;
    if (bx < 25) { A = enc; W = Wenc; bias = b_enc; C = enc_p; M = 1600; }
    else { bx -= 25; A = dec; W = Wdec; bias = b_dec; C = dec_p; M = 400; }

    int tid = threadIdx.x;
    int lane = tid & 63, wv = tid >> 6;
    int wm = wv >> 1, wn = wv & 1;          // 2x2 wave grid, wave tile 32x32
    int l16 = lane & 15, q4 = lane >> 4;

    int ra = tid >> 2, ha = tid & 3;        // stage: row 0..63, 16-float k-chunk
    int m_st = bx * 64 + ra;
    bool valid = m_st < M;
    int wrow = by * 64 + ra;                // always < 512

    floatx4 acc[2][2];
    #pragma unroll
    for (int a = 0; a < 2; a++)
        #pragma unroll
        for (int b = 0; b < 2; b++) acc[a][b] = (floatx4){0.f, 0.f, 0.f, 0.f};

    for (int kk = 0; kk < 8; kk++) {
        int k0 = kk * 64;
        __syncthreads();
        {
            // ---- A tile: 64 rows x 64 k, fp32 -> bf16
            float4 v0 = make_float4(0.f, 0.f, 0.f, 0.f);
            float4 v1 = v0, v2 = v0, v3 = v0;
            if (valid) {
                const float4* p = (const float4*)(A + (size_t)m_st * JD + k0 + ha * 16);
                v0 = p[0]; v1 = p[1]; v2 = p[2]; v3 = p[3];
            }
            short8 o0, o1;
            o0[0] = f2bf(v0.x); o0[1] = f2bf(v0.y); o0[2] = f2bf(v0.z); o0[3] = f2bf(v0.w);
            o0[4] = f2bf(v1.x); o0[5] = f2bf(v1.y); o0[6] = f2bf(v1.z); o0[7] = f2bf(v1.w);
            o1[0] = f2bf(v2.x); o1[1] = f2bf(v2.y); o1[2] = f2bf(v2.z); o1[3] = f2bf(v2.w);
            o1[4] = f2bf(v3.x); o1[5] = f2bf(v3.y); o1[6] = f2bf(v3.z); o1[7] = f2bf(v3.w);
            *(short8*)&As[ra * PST + ha * 16]     = o0;
            *(short8*)&As[ra * PST + ha * 16 + 8] = o1;

            // ---- B tile: 64 rows x 64 k, fp32 -> bf16
            const float4* pb = (const float4*)(W + (size_t)wrow * JD + k0 + ha * 16);
            float4 w0 = pb[0], w1 = pb[1], w2 = pb[2], w3 = pb[3];
            short8 p0, p1;
            p0[0] = f2bf(w0.x); p0[1] = f2bf(w0.y); p0[2] = f2bf(w0.z); p0[3] = f2bf(w0.w);
            p0[4] = f2bf(w1.x); p0[5] = f2bf(w1.y); p0[6] = f2bf(w1.z); p0[7] = f2bf(w1.w);
            p1[0] = f2bf(w2.x); p1[1] = f2bf(w2.y); p1[2] = f2bf(w2.z); p1[3] = f2bf(w2.w);
            p1[4] = f2bf(w3.x); p1[5] = f2bf(w3.y); p1[6] = f2bf(w3.z); p1[7] = f2bf(w3.w);
            *(short8*)&Bs[ra * PST + ha * 16]     = p0;
            *(short8*)&Bs[ra * PST + ha * 16 + 8] = p1;
        }
        __syncthreads();
        #pragma unroll
        for (int h2 = 0; h2 < 2; h2++) {
            short8 af[2], bf[2];
            #pragma unroll
            for (int im = 0; im < 2; im++)
                af[im] = *(const short8*)&As[(wm * 32 + im * 16 + l16) * PST + h2 * 32 + q4 * 8];
            #pragma unroll
            for (int in = 0; in < 2; in++)
                bf[in] = *(const short8*)&Bs[(wn * 32 + in * 16 + l16) * PST + h2 * 32 + q4 * 8];
            #pragma unroll
            for (int im = 0; im < 2; im++)
                #pragma unroll
                for (int in = 0; in < 2; in++)
                    acc[im][in] = __builtin_amdgcn_mfma_f32_16x16x32_bf16(
                        af[im], bf[in], acc[im][in], 0, 0, 0);
        }
    }
    #pragma unroll
    for (int im = 0; im < 2; im++) {
        int mb = bx * 64 + wm * 32 + im * 16 + q4 * 4;
        #pragma unroll
        for (int rr = 0; rr < 4; rr++) {
            int m = mb + rr;
            if (m < M) {
                #pragma unroll
                for (int in = 0; in < 2; in++) {
                    int j = by * 64 + wn * 32 + in * 16 + l16;
                    C[(size_t)m * JD + j] = acc[im][in][rr] + bias[j];
                }
            }
        }
    }
}

// ---------------------------------------------------------------------------
// Kernel 3: FUSED act + vocab GEMM — v5: PERSISTENT-B.
// Diagnosis r3/r4: neither occupancy (r4) nor double-buffering (r3) moved the
// 100 µs — the structure re-streamed WbF through L1/L2 every 64 output rows
// (>1 GB of L2 B-reads) with per-ks load latency on the critical path.
// Now each wave holds its ENTIRE B stripe (32 v-cols x 512 k) in 128 VGPRs:
//   - grid (125 m-groups x 2 v-halves) = 250 blocks ~ 1/CU, no drain wave
//   - block = 8 waves x 32 v = 256 v; B preloaded ONCE (256 KB/block,
//     64 MB chip-wide vs 1.25 GB in r4)
//   - each block loops 10 act-tiles of 64 m-rows; LDS double-buffered
//     (2 x 66,560 B = 133,120 B); ONE barrier per tile (buffer freed by
//     program-order: stage(t+1) < bar(t+1) < stage(t+2) reuse)
//   - k-loop reads ONLY LDS (act frags) + registers (B): no global access
//     in the MFMA critical path; acc is a transient 8-reg pair per m-subtile
// Budget: 128 (B) + 8 (acc) + stage/addr ~50 => ~190 regs, 2 waves/SIMD.
// Stores: plain (r4's nontemporal caused +42 MB partial-line RMW; reverted).
// ---------------------------------------------------------------------------
#define AST 520
__global__ __launch_bounds__(512, 2) void fused_joiner(
    const float* __restrict__ enc_p, const float* __restrict__ dec_p,
    const short* __restrict__ WbF, const float* __restrict__ b_out,
    float* __restrict__ out)
{
    __shared__ short As[2][64 * AST];   // 133,120 B total
    int tid = threadIdx.x;
    int mgrp = blockIdx.x;              // 0..124 (10 tiles of 64 rows each)
    int vg   = blockIdx.y;              // 0..1   (v 0..255 / 256..511)
    int lane = tid & 63, wv = tid >> 6;
    int l16 = lane & 15, q4 = lane >> 4;

    // Wave's v-columns under the WbF fragment layout:
    //   v = wn*128 + in*16 + l16 with wn = vg*2 + (wv>>2), in = (wv&3)*2 + f
    int wn  = vg * 2 + (wv >> 2);
    int in0 = (wv & 3) * 2;
    int vb0 = wn * 128 + in0 * 16;      // f=0 stripe base; f=1 is +16

    // ---- B preload: 32 v x 512 k in 128 VGPRs (once per block)
    short8 breg0[16], breg1[16];
    {
        const short* bp = WbF + q4 * 128 + l16 * 8 + (wn * 8 + in0) * 512;
        #pragma unroll
        for (int ks = 0; ks < 16; ks++) {
            breg0[ks] = *(const short8*)(bp + ks * 16384);
            breg1[ks] = *(const short8*)(bp + ks * 16384 + 512);
        }
    }

    float bo0, bo1;
    {
        int v0 = vb0 + l16, v1 = vb0 + 16 + l16;
        bo0 = (v0 < VV) ? b_out[v0] : 0.f;
        bo1 = (v1 < VV) ? b_out[v1] : 0.f;
    }

    int rsub = tid >> 7;                // 0..3 rows per staging pass
    int jf   = (tid & 127) * 4;         // fp32 j offset, coalesced per row

    for (int t = 0; t < 10; t++) {
        int m0 = (mgrp * 10 + t) * 64;
        short* buf = &As[t & 1][0];

        // ---- stage act tile (64 m-rows x 512 j) -> LDS buf
        #pragma unroll 4
        for (int pass = 0; pass < 16; pass++) {
            int row = pass * 4 + rsub;
            int m = m0 + row;
            int er = m / 50;            // n*200 + t
            int n  = m / 10000;
            int dr = n * 50 + (m - er * 50);
            float4 e = *(const float4*)(enc_p + (size_t)er * JD + jf);
            float4 d = *(const float4*)(dec_p + (size_t)dr * JD + jf);
            short4v o;
            o[0] = f2bf(fast_tanh(e.x + d.x));
            o[1] = f2bf(fast_tanh(e.y + d.y));
            o[2] = f2bf(fast_tanh(e.z + d.z));
            o[3] = f2bf(fast_tanh(e.w + d.w));
            *(short4v*)&buf[row * AST + jf] = o;
        }
        __syncthreads();

        // ---- compute + store: 4 m-subtiles x (16 ks x 2 v-frags) MFMAs
        #pragma unroll
        for (int ms = 0; ms < 4; ms++) {
            int ab = (ms * 16 + l16) * AST + q4 * 8;
            floatx4 a0 = (floatx4){0.f, 0.f, 0.f, 0.f};
            floatx4 a1 = (floatx4){0.f, 0.f, 0.f, 0.f};
            #pragma unroll
            for (int ks = 0; ks < 16; ks++) {
                short8 af = *(const short8*)&buf[ab + ks * 32];
                a0 = __builtin_amdgcn_mfma_f32_16x16x32_bf16(af, breg0[ks], a0, 0, 0, 0);
                a1 = __builtin_amdgcn_mfma_f32_16x16x32_bf16(af, breg1[ks], a1, 0, 0, 0);
            }
            int v0 = vb0 + l16, v1 = vb0 + 16 + l16;
            #pragma unroll
            for (int rr = 0; rr < 4; rr++) {
                size_t orow = (size_t)(m0 + ms * 16 + q4 * 4 + rr) * VV;
                if (v0 < VV) out[orow + v0] = a0[rr] + bo0;
                if (v1 < VV) out[orow + v1] = a1[rr] + bo1;
            }
        }
    }
}

// ---------------------------------------------------------------------------
extern "C" void kernel_launch(void* const* d_in, const int* in_sizes, int n_in,
                              void* d_out, int out_size, void* d_ws, size_t ws_size,
                              hipStream_t stream)
{
    const float* enc   = (const float*)d_in[0];
    const float* dec   = (const float*)d_in[1];
    const float* Wenc  = (const float*)d_in[2];
    const float* b_enc = (const float*)d_in[3];
    const float* Wdec  = (const float*)d_in[4];
    const float* b_dec = (const float*)d_in[5];
    const float* Wout  = (const float*)d_in[6];
    const float* b_out = (const float*)d_in[7];
    float* out = (float*)d_out;

    // ws layout (bytes): ~4.6 MB total
    char* ws = (char*)d_ws;
    short* WbF   = (short*)(ws + 0);          // 512*512 bf16 = 524,288 B
    float* enc_p = (float*)(ws + 524288);     // 1600*512 f32 = 3,276,800 B
    float* dec_p = (float*)(ws + 3801088);    //  400*512 f32 =   819,200 B

    prep_kernel<<<128, 256, 0, stream>>>(Wout, WbF);
    proj_gemm<<<dim3(32, 8), 256, 0, stream>>>(enc, dec, Wenc, Wdec,
                                               b_enc, b_dec, enc_p, dec_p);
    fused_joiner<<<dim3(125, 2), 512, 0, stream>>>(enc_p, dec_p, WbF, b_out, out);
}

// Round 7
// 233.965 us; speedup vs baseline: 1.0988x; 1.0187x over previous
//
#include <hip/hip_runtime.h>
#include <hip/hip_bf16.h>
#include <stdint.h>

// Problem constants: N=8, T=200, U=50, E=D=J=512, V=500. M = N*T*U = 80000.
#define JD 512
#define VV 500

typedef short short8 __attribute__((ext_vector_type(8)));
typedef short short4v __attribute__((ext_vector_type(4)));
typedef float floatx4 __attribute__((ext_vector_type(4)));

__device__ inline short f2bf(float f) {
    uint32_t u = __float_as_uint(f);
    uint32_t r = (u + 0x7FFFu + ((u >> 16) & 1u)) >> 16;
    return (short)r;
}

__device__ inline float fast_tanh(float x) {
    // tanh(x) = 1 - 2/(exp(2x)+1); v_exp_f32 is exp2 natively.
    float e = __builtin_amdgcn_exp2f(x * 2.8853900817779268f); // 2*log2(e)
    return 1.0f - 2.0f * __builtin_amdgcn_rcpf(e + 1.0f);
}

// ---------------------------------------------------------------------------
// Kernel 1: W_out -> WbF, fragment-native order (unchanged since round 3):
//   short index = ((ks*4 + wn)*8 + in)*512 + q4*128 + l16*8 + e
//   holds Wout[v = wn*128 + in*16 + l16][k = ks*32 + q4*8 + e], zero-padded
//   v 500..511. A wave's B-fragment load is one contiguous 1 KiB read.
// ---------------------------------------------------------------------------
__global__ __launch_bounds__(256) void prep_kernel(
    const float* __restrict__ Wout, short* __restrict__ WbF)
{
    int j = blockIdx.x * 256 + threadIdx.x;   // 0..32767, 8 shorts each
    int l16 = j & 15;
    int q4  = (j >> 4) & 3;
    int in  = (j >> 6) & 7;
    int wn  = (j >> 9) & 3;
    int ks  = j >> 11;                         // 0..15
    int v  = wn * 128 + in * 16 + l16;
    int k0 = ks * 32 + q4 * 8;
    short8 o;
    if (v < VV) {
        const float4* p = (const float4*)(Wout + (size_t)v * JD + k0);
        float4 a = p[0], b = p[1];
        o[0] = f2bf(a.x); o[1] = f2bf(a.y); o[2] = f2bf(a.z); o[3] = f2bf(a.w);
        o[4] = f2bf(b.x); o[5] = f2bf(b.y); o[6] = f2bf(b.z); o[7] = f2bf(b.w);
    } else {
        o = (short8){0,0,0,0,0,0,0,0};
    }
    *(short8*)(WbF + (size_t)j * 8) = o;       // coalesced 16 B/lane
}

// ---------------------------------------------------------------------------
// Kernel 2: projection GEMMs (enc: 1600x512x512, dec: 400x512x512).
// v2 (round 7): full-K panel staged ONCE (2 x 66.5 KB LDS), ONE barrier
// instead of 16; all 32 staging loads in flight together; then 16 straight
// k-steps with 4 interleaved MFMA chains. Was ~40 us with 16 barriers and
// 2-MFMA bursts per barrier; the loop was barrier/latency-bound, not
// compute- or BW-bound (1 GFLOP / 64 MB total).
// ---------------------------------------------------------------------------
#define QST 520
__global__ __launch_bounds__(256) void proj_gemm(
    const float* __restrict__ enc, const float* __restrict__ dec,
    const float* __restrict__ Wenc, const float* __restrict__ Wdec,
    const float* __restrict__ b_enc, const float* __restrict__ b_dec,
    float* __restrict__ enc_p, float* __restrict__ dec_p)
{
    __shared__ short As[64 * QST];    // 66,560 B
    __shared__ short Bs[64 * QST];    // 66,560 B (133,120 total)
    int bx = blockIdx.x, by = blockIdx.y;
    const float* A; const float* W; const float* bias; float* C; int M;
    if (bx < 25) { A = enc; W = Wenc; bias = b_enc; C = enc_p; M = 1600; }
    else { bx -= 25; A = dec; W = Wdec; bias = b_dec; C = dec_p; M = 400; }

    int tid = threadIdx.x;
    int lane = tid & 63, wv = tid >> 6;
    int wm = wv >> 1, wn = wv & 1;          // 2x2 wave grid, wave tile 32x32
    int l16 = lane & 15, q4 = lane >> 4;

    int ra = tid >> 2, ha = tid & 3;        // stage: row 0..63, 16-float chunks
    int m_st = bx * 64 + ra;
    bool valid = m_st < M;
    int wrow = by * 64 + ra;                // always < 512

    // ---- stage full 64 x 512 panels (A and W), fp32 -> bf16, one pass
    #pragma unroll
    for (int c = 0; c < 8; c++) {
        int k0 = c * 64 + ha * 16;
        float4 v0 = make_float4(0.f, 0.f, 0.f, 0.f);
        float4 v1 = v0, v2 = v0, v3 = v0;
        if (valid) {
            const float4* p = (const float4*)(A + (size_t)m_st * JD + k0);
            v0 = p[0]; v1 = p[1]; v2 = p[2]; v3 = p[3];
        }
        const float4* pb = (const float4*)(W + (size_t)wrow * JD + k0);
        float4 w0 = pb[0], w1 = pb[1], w2 = pb[2], w3 = pb[3];
        short8 o0, o1, p0, p1;
        o0[0] = f2bf(v0.x); o0[1] = f2bf(v0.y); o0[2] = f2bf(v0.z); o0[3] = f2bf(v0.w);
        o0[4] = f2bf(v1.x); o0[5] = f2bf(v1.y); o0[6] = f2bf(v1.z); o0[7] = f2bf(v1.w);
        o1[0] = f2bf(v2.x); o1[1] = f2bf(v2.y); o1[2] = f2bf(v2.z); o1[3] = f2bf(v2.w);
        o1[4] = f2bf(v3.x); o1[5] = f2bf(v3.y); o1[6] = f2bf(v3.z); o1[7] = f2bf(v3.w);
        p0[0] = f2bf(w0.x); p0[1] = f2bf(w0.y); p0[2] = f2bf(w0.z); p0[3] = f2bf(w0.w);
        p0[4] = f2bf(w1.x); p0[5] = f2bf(w1.y); p0[6] = f2bf(w1.z); p0[7] = f2bf(w1.w);
        p1[0] = f2bf(w2.x); p1[1] = f2bf(w2.y); p1[2] = f2bf(w2.z); p1[3] = f2bf(w2.w);
        p1[4] = f2bf(w3.x); p1[5] = f2bf(w3.y); p1[6] = f2bf(w3.z); p1[7] = f2bf(w3.w);
        *(short8*)&As[ra * QST + k0]     = o0;
        *(short8*)&As[ra * QST + k0 + 8] = o1;
        *(short8*)&Bs[ra * QST + k0]     = p0;
        *(short8*)&Bs[ra * QST + k0 + 8] = p1;
    }
    __syncthreads();

    // ---- 16 k-steps, 4 interleaved MFMA chains
    floatx4 acc[2][2];
    #pragma unroll
    for (int a = 0; a < 2; a++)
        #pragma unroll
        for (int b = 0; b < 2; b++) acc[a][b] = (floatx4){0.f, 0.f, 0.f, 0.f};

    #pragma unroll
    for (int ks = 0; ks < 16; ks++) {
        int ko = ks * 32 + q4 * 8;
        short8 af[2], bf[2];
        #pragma unroll
        for (int im = 0; im < 2; im++)
            af[im] = *(const short8*)&As[(wm * 32 + im * 16 + l16) * QST + ko];
        #pragma unroll
        for (int in = 0; in < 2; in++)
            bf[in] = *(const short8*)&Bs[(wn * 32 + in * 16 + l16) * QST + ko];
        #pragma unroll
        for (int im = 0; im < 2; im++)
            #pragma unroll
            for (int in = 0; in < 2; in++)
                acc[im][in] = __builtin_amdgcn_mfma_f32_16x16x32_bf16(
                    af[im], bf[in], acc[im][in], 0, 0, 0);
    }

    #pragma unroll
    for (int im = 0; im < 2; im++) {
        int mb = bx * 64 + wm * 32 + im * 16 + q4 * 4;
        #pragma unroll
        for (int rr = 0; rr < 4; rr++) {
            int m = mb + rr;
            if (m < M) {
                #pragma unroll
                for (int in = 0; in < 2; in++) {
                    int j = by * 64 + wn * 32 + in * 16 + l16;
                    C[(size_t)m * JD + j] = acc[im][in][rr] + bias[j];
                }
            }
        }
    }
}

// ---------------------------------------------------------------------------
// Kernel 3: FUSED act + vocab GEMM — v6: persistent-B + T14 overlap.
// r6 post-mortem: persistent-B (r5) removed B-traffic but at 1 block/CU the
// tile loop was phase-serialized: [stage ~3.5k VALU cyc] -> bar -> [MFMA]
// with nothing filling MFMA chain stalls. Now per ms-subtile:
//   1. ISSUE tile-(t+1) global loads (8 float4) -- no wait
//   2. run the 32-MFMA chain pair (covers the load latency)
//   3. tanh + ds_write the returned data into the other LDS buffer
//   4. store this ms-subtile's acc
// Double buffer makes one barrier per tile sufficient: stage(t+1) writes
// buf[(t+1)&1], last read in compute(t-1) which all waves finished at bar(t).
// B stripe: 32 v x 512 k in 128 VGPRs preloaded once (unchanged from r5).
// ---------------------------------------------------------------------------
#define AST 520
__global__ __launch_bounds__(512, 2) void fused_joiner(
    const float* __restrict__ enc_p, const float* __restrict__ dec_p,
    const short* __restrict__ WbF, const float* __restrict__ b_out,
    float* __restrict__ out)
{
    __shared__ short As[2][64 * AST];   // 133,120 B total
    int tid = threadIdx.x;
    int mgrp = blockIdx.x;              // 0..124 (10 tiles of 64 rows each)
    int vg   = blockIdx.y;              // 0..1   (v 0..255 / 256..511)
    int lane = tid & 63, wv = tid >> 6;
    int l16 = lane & 15, q4 = lane >> 4;

    int wn  = vg * 2 + (wv >> 2);
    int in0 = (wv & 3) * 2;
    int vb0 = wn * 128 + in0 * 16;

    // ---- B preload: 32 v x 512 k in 128 VGPRs (once per block)
    short8 breg0[16], breg1[16];
    {
        const short* bp = WbF + q4 * 128 + l16 * 8 + (wn * 8 + in0) * 512;
        #pragma unroll
        for (int ks = 0; ks < 16; ks++) {
            breg0[ks] = *(const short8*)(bp + ks * 16384);
            breg1[ks] = *(const short8*)(bp + ks * 16384 + 512);
        }
    }

    float bo0, bo1;
    {
        int v0 = vb0 + l16, v1 = vb0 + 16 + l16;
        bo0 = (v0 < VV) ? b_out[v0] : 0.f;
        bo1 = (v1 < VV) ? b_out[v1] : 0.f;
    }

    int rsub = tid >> 7;                // 0..3
    int jf   = (tid & 127) * 4;         // fp32 j offset, coalesced per row

    // ---- prologue: stage tile 0 fully
    {
        int m0 = mgrp * 640;
        #pragma unroll 4
        for (int pass = 0; pass < 16; pass++) {
            int row = pass * 4 + rsub;
            int m = m0 + row;
            int er = m / 50;
            int n  = m / 10000;
            int dr = n * 50 + (m - er * 50);
            float4 e = *(const float4*)(enc_p + (size_t)er * JD + jf);
            float4 d = *(const float4*)(dec_p + (size_t)dr * JD + jf);
            short4v o;
            o[0] = f2bf(fast_tanh(e.x + d.x));
            o[1] = f2bf(fast_tanh(e.y + d.y));
            o[2] = f2bf(fast_tanh(e.z + d.z));
            o[3] = f2bf(fast_tanh(e.w + d.w));
            *(short4v*)&As[0][row * AST + jf] = o;
        }
    }
    __syncthreads();

    for (int t = 0; t < 10; t++) {
        int m0 = (mgrp * 10 + t) * 64;
        const short* buf = &As[t & 1][0];
        short* nbuf = &As[(t + 1) & 1][0];
        int m0n = m0 + 64;
        bool pf = (t < 9);

        #pragma unroll
        for (int ms = 0; ms < 4; ms++) {
            // 1. issue next-tile loads for staging chunk ms (rows ms*16..+15)
            float4 pe[4], pd[4];
            int prow[4];
            if (pf) {
                #pragma unroll
                for (int p = 0; p < 4; p++) {
                    int row = ms * 16 + p * 4 + rsub;
                    int m = m0n + row;
                    int er = m / 50;
                    int n  = m / 10000;
                    int dr = n * 50 + (m - er * 50);
                    prow[p] = row;
                    pe[p] = *(const float4*)(enc_p + (size_t)er * JD + jf);
                    pd[p] = *(const float4*)(dec_p + (size_t)dr * JD + jf);
                }
            }

            // 2. MFMA chain pair for this ms (covers load latency)
            int ab = (ms * 16 + l16) * AST + q4 * 8;
            floatx4 a0 = (floatx4){0.f, 0.f, 0.f, 0.f};
            floatx4 a1 = (floatx4){0.f, 0.f, 0.f, 0.f};
            #pragma unroll
            for (int ks = 0; ks < 16; ks++) {
                short8 af = *(const short8*)&buf[ab + ks * 32];
                a0 = __builtin_amdgcn_mfma_f32_16x16x32_bf16(af, breg0[ks], a0, 0, 0, 0);
                a1 = __builtin_amdgcn_mfma_f32_16x16x32_bf16(af, breg1[ks], a1, 0, 0, 0);
            }

            // 3. tanh + LDS write of the prefetched chunk
            if (pf) {
                #pragma unroll
                for (int p = 0; p < 4; p++) {
                    short4v o;
                    o[0] = f2bf(fast_tanh(pe[p].x + pd[p].x));
                    o[1] = f2bf(fast_tanh(pe[p].y + pd[p].y));
                    o[2] = f2bf(fast_tanh(pe[p].z + pd[p].z));
                    o[3] = f2bf(fast_tanh(pe[p].w + pd[p].w));
                    *(short4v*)&nbuf[prow[p] * AST + jf] = o;
                }
            }

            // 4. store this ms-subtile
            int v0 = vb0 + l16, v1 = vb0 + 16 + l16;
            #pragma unroll
            for (int rr = 0; rr < 4; rr++) {
                size_t orow = (size_t)(m0 + ms * 16 + q4 * 4 + rr) * VV;
                if (v0 < VV) out[orow + v0] = a0[rr] + bo0;
                if (v1 < VV) out[orow + v1] = a1[rr] + bo1;
            }
        }
        __syncthreads();
    }
}

// ---------------------------------------------------------------------------
extern "C" void kernel_launch(void* const* d_in, const int* in_sizes, int n_in,
                              void* d_out, int out_size, void* d_ws, size_t ws_size,
                              hipStream_t stream)
{
    const float* enc   = (const float*)d_in[0];
    const float* dec   = (const float*)d_in[1];
    const float* Wenc  = (const float*)d_in[2];
    const float* b_enc = (const float*)d_in[3];
    const float* Wdec  = (const float*)d_in[4];
    const float* b_dec = (const float*)d_in[5];
    const float* Wout  = (const float*)d_in[6];
    const float* b_out = (const float*)d_in[7];
    float* out = (float*)d_out;

    // ws layout (bytes): ~4.6 MB total
    char* ws = (char*)d_ws;
    short* WbF   = (short*)(ws + 0);          // 512*512 bf16 = 524,288 B
    float* enc_p = (float*)(ws + 524288);     // 1600*512 f32 = 3,276,800 B
    float* dec_p = (float*)(ws + 3801088);    //  400*512 f32 =   819,200 B

    prep_kernel<<<128, 256, 0, stream>>>(Wout, WbF);
    proj_gemm<<<dim3(32, 8), 256, 0, stream>>>(enc, dec, Wenc, Wdec,
                                               b_enc, b_dec, enc_p, dec_p);
    fused_joiner<<<dim3(125, 2), 512, 0, stream>>>(enc_p, dec_p, WbF, b_out, out);
}